// Round 6
// baseline (265.470 us; speedup 1.0000x reference)
//
#include <hip/hip_runtime.h>
#include <math.h>

typedef __attribute__((ext_vector_type(8))) _Float16 half8;
typedef __attribute__((ext_vector_type(4))) float    f32x4;

constexpr int D_DIM = 2048;
constexpr int NEXP  = 64;
constexpr int TOPK  = 8;
constexpr int NTOK  = 16384;        // B*S
constexpr int TM    = 16;           // tokens per WG
constexpr int BK    = 128;          // K per staged region (4 MFMA ksteps)
constexpr int NREG  = D_DIM / BK;   // 16 regions
constexpr int OSTR  = 132;          // logit tile row stride (floats)
constexpr int NSTR  = 68;           // noise tile row stride (floats)
constexpr float WSCALE  = 4096.0f;  // W pre-scale (keeps fp16 lo out of subnormals)
constexpr float INV_WSC = 1.0f / 4096.0f;

__device__ __forceinline__ unsigned short f16b(float x) {
    _Float16 h = (_Float16)x;                       // v_cvt_f16_f32 (RNE)
    return __builtin_bit_cast(unsigned short, h);
}
__device__ __forceinline__ float f16tof(unsigned short b) {
    return (float)__builtin_bit_cast(_Float16, b);
}

// ---------------------------------------------------------------------------
// K1: split W*4096 (gate rows 0..63, noise rows 64..127) into fp16 hi/lo,
// packed B-fragment-linear: ws ushort layout
//   [kstep32 g (stride 8192)][ntile T (stride 1024)]{ hi 512 | lo 512 }
//   lane l holds B[k = g*32 + (l>>4)*8 + j][n = T*16 + (l&15)]
// ---------------------------------------------------------------------------
__global__ void prep_w(const float* __restrict__ Wg, const float* __restrict__ Wn,
                       unsigned short* __restrict__ wsB)
{
    const int idx = blockIdx.x * blockDim.x + threadIdx.x;   // 0..32767
    const int n   = idx >> 8;      // output row 0..127
    const int K8  = idx & 255;     // k-octet
    const float* src = (n < 64) ? (Wg + (size_t)n * D_DIM)
                                : (Wn + (size_t)(n - 64) * D_DIM);
    float4 a = *reinterpret_cast<const float4*>(src + K8 * 8);
    float4 b = *reinterpret_cast<const float4*>(src + K8 * 8 + 4);

    float v[8] = {a.x, a.y, a.z, a.w, b.x, b.y, b.z, b.w};
    union { unsigned short u[8]; half8 s; } H, L;
#pragma unroll
    for (int j = 0; j < 8; ++j) {
        float xs = v[j] * WSCALE;
        unsigned short h = f16b(xs);
        H.u[j] = h;
        L.u[j] = f16b(xs - f16tof(h));
    }
    const int l = ((K8 & 3) * 16) + (n & 15);
    const size_t base = (size_t)(K8 >> 2) * 8192 + (size_t)(n >> 4) * 1024 + (size_t)l * 8;
    *reinterpret_cast<half8*>(wsB + base)       = H.s;
    *reinterpret_cast<half8*>(wsB + base + 512) = L.s;
}

// ---------------------------------------------------------------------------
// K2: TM=16 tok/WG, block=256 (4 waves x 2 n-tiles), grid 1024 (4 WGs/CU).
// BK=128 regions, XOR-swizzled b128 staging (conflict-free), B loads issued
// BEFORE the A prefetch each region (vmcnt retires in order: B-consumers
// never wait on the HBM A load). Region-c data needs no waits (prior barrier
// drained it).
// ---------------------------------------------------------------------------
__global__ __launch_bounds__(256, 4)
void noisy_topk_router(const float* __restrict__ hs,
                       const unsigned short* __restrict__ wsB,
                       const float* __restrict__ nz,
                       float* __restrict__ out)
{
    // stage: 2 bufs x 4096 ushorts (8 KB: hi 2048 | lo 2048) = 16 KB
    // epilogue union: logits 16x132 f32 (8448 B) + noise 16x68 f32 (4352 B)
    __shared__ __align__(16) char smem[16384];
    unsigned short* stage  = reinterpret_cast<unsigned short*>(smem);
    float*          logits = reinterpret_cast<float*>(smem);
    float*          ldsN   = reinterpret_cast<float*>(smem + 8448);

    const int tid  = threadIdx.x;
    const int lane = tid & 63;
    const int w    = tid >> 6;          // wave 0..3 -> ntiles {2w, 2w+1}
    const int t0   = blockIdx.x * TM;

    // ---- staging role: thread owns 8 consecutive k of one row ----
    const int row  = tid >> 4;          // 0..15
    const int oct  = tid & 15;          // k-octet within 128
    const int ks_s = oct >> 2;          // kstep32 within region
    const int j0_s = oct & 3;           // k-octet within kstep
    const float* hrow = hs + (size_t)(t0 + row) * D_DIM + oct * 8;
    // fragment lane this thread's data belongs to, and swizzled 16B-block slot
    const int lane_w = j0_s * 16 + row;
    const int wr_hi  = (ks_s * 64 + (lane_w ^ (j0_s << 1) ^ ks_s)) * 8;   // ushort units

    // ---- A-fragment read offsets (swizzle-matched), per kstep ----
    const int l_sw = lane ^ ((lane >> 4) << 1);
    int aoff[4];
#pragma unroll
    for (int ks = 0; ks < 4; ++ks)
        aoff[ks] = (ks * 64 + (l_sw ^ ks)) * 8;

    f32x4 accH[2][2], accX[2];
#pragma unroll
    for (int nt = 0; nt < 2; ++nt) {
        accH[0][nt] = (f32x4){0.f, 0.f, 0.f, 0.f};
        accH[1][nt] = (f32x4){0.f, 0.f, 0.f, 0.f};
        accX[nt]    = (f32x4){0.f, 0.f, 0.f, 0.f};
    }

    auto cvt_write = [&](float4 v0, float4 v1, unsigned short* buf) {
        float x[8] = {v0.x, v0.y, v0.z, v0.w, v1.x, v1.y, v1.z, v1.w};
        union { unsigned short u[8]; half8 s; } H, L;
#pragma unroll
        for (int j = 0; j < 8; ++j) {
            unsigned short h = f16b(x[j]);
            H.u[j] = h;
            L.u[j] = f16b(x[j] - f16tof(h));
        }
        *reinterpret_cast<half8*>(buf + wr_hi)        = H.s;   // ds_write_b128
        *reinterpret_cast<half8*>(buf + 2048 + wr_hi) = L.s;
    };

    // prologue: stage region 0
    cvt_write(*reinterpret_cast<const float4*>(hrow),
              *reinterpret_cast<const float4*>(hrow + 4), stage);
    __syncthreads();

    const unsigned short* bwave = wsB + (size_t)(2 * w) * 1024 + (size_t)lane * 8;

    for (int c = 0; c < NREG; ++c) {
        // 1. B loads FIRST (L2; consumed this region — waits won't touch A)
        half8 bh[4][2], bl[4][2];
#pragma unroll
        for (int ks = 0; ks < 4; ++ks) {
            const unsigned short* bp = bwave + (size_t)(c * 4 + ks) * 8192;
            bh[ks][0] = *reinterpret_cast<const half8*>(bp);
            bl[ks][0] = *reinterpret_cast<const half8*>(bp + 512);
            bh[ks][1] = *reinterpret_cast<const half8*>(bp + 1024);
            bl[ks][1] = *reinterpret_cast<const half8*>(bp + 1536);
        }
        // 2. A prefetch LAST (HBM; consumed at region end by cvt_write —
        //    by then all B loads are retired, so vmcnt(0) costs only residual)
        float4 p0, p1;
        if (c + 1 < NREG) {
            p0 = *reinterpret_cast<const float4*>(hrow + (c + 1) * BK);
            p1 = *reinterpret_cast<const float4*>(hrow + (c + 1) * BK + 4);
        }

        // 3. MFMAs on region-c data (LDS reads need no global waits)
        const unsigned short* sb = stage + (c & 1) * 4096;
#pragma unroll
        for (int ks = 0; ks < 4; ++ks) {
            half8 ahi = *reinterpret_cast<const half8*>(sb + aoff[ks]);
            half8 alo = *reinterpret_cast<const half8*>(sb + 2048 + aoff[ks]);
#pragma unroll
            for (int nt = 0; nt < 2; ++nt) {
                accH[ks & 1][nt] = __builtin_amdgcn_mfma_f32_16x16x32_f16(ahi, bh[ks][nt], accH[ks & 1][nt], 0, 0, 0);
                accX[nt]         = __builtin_amdgcn_mfma_f32_16x16x32_f16(ahi, bl[ks][nt], accX[nt], 0, 0, 0);
                accX[nt]         = __builtin_amdgcn_mfma_f32_16x16x32_f16(alo, bh[ks][nt], accX[nt], 0, 0, 0);
            }
        }

        // 4. stage next region into the other buffer
        if (c + 1 < NREG)
            cvt_write(p0, p1, stage + ((c + 1) & 1) * 4096);
        __syncthreads();
    }

    // ---- epilogue: D[row=(lane>>4)*4+reg][col=lane&15], ntiles 2w,2w+1 ----
    {
        const int rowb = (lane >> 4) * 4;
        const int colw = lane & 15;
#pragma unroll
        for (int nt = 0; nt < 2; ++nt) {
            const int colb = (2 * w + nt) * 16 + colw;
#pragma unroll
            for (int r = 0; r < 4; ++r)
                logits[(rowb + r) * OSTR + colb] =
                    (accH[0][nt][r] + accH[1][nt][r] + accX[nt][r]) * INV_WSC;
        }
    }
    // stage noise tile coalesced: 256 threads x 1 float4 = 16 rows x 64 floats
    {
        const int rr = tid >> 4;
        const int cc = tid & 15;
        float4 v = *reinterpret_cast<const float4*>(nz + (size_t)(t0 + rr) * NEXP + cc * 4);
        *reinterpret_cast<float4*>(&ldsN[rr * NSTR + cc * 4]) = v;
    }
    __syncthreads();

    if (tid < TM) {
        const int tok = t0 + tid;
        float l[NEXP];
        float mx = -3.0e38f;
#pragma unroll
        for (int e = 0; e < NEXP; ++e) {
            float gsc = logits[tid * OSTR + e];
            float nl  = logits[tid * OSTR + 64 + e];
            float sp  = fmaxf(nl, 0.0f) + log1pf(expf(-fabsf(nl)));   // softplus
            float le  = fmaf(ldsN[tid * NSTR + e], sp, gsc);
            l[e] = le;
            mx = fmaxf(mx, le);
        }
        float sum = 0.0f;
#pragma unroll
        for (int e = 0; e < NEXP; ++e) { float p = expf(l[e] - mx); l[e] = p; sum += p; }
        float inv = 1.0f / sum;
#pragma unroll
        for (int e = 0; e < NEXP; ++e) l[e] *= inv;

        // save gates for coalesced store
#pragma unroll
        for (int e = 0; e < NEXP; ++e) logits[tid * OSTR + e] = l[e];

        float* vout = out + (size_t)tok * TOPK;
        float* iout = out + (size_t)NTOK * TOPK + (size_t)tok * TOPK;
#pragma unroll
        for (int p = 0; p < TOPK; ++p) {
            float m = -1.0f; int mi = 0;
#pragma unroll
            for (int e = 0; e < NEXP; ++e) {
                bool gt = l[e] > m;        // strict > + ascending scan = lowest-index tie-break
                m  = gt ? l[e] : m;
                mi = gt ? e : mi;
            }
            vout[p] = m;
            iout[p] = (float)mi;
#pragma unroll
            for (int e = 0; e < NEXP; ++e) l[e] = (e == mi) ? -1.0f : l[e];
        }
    }
    __syncthreads();

    // coalesced gates store: 256 threads x 1 float4
    {
        const int rr = tid >> 4;
        const int cc = tid & 15;
        float* gout = out + (size_t)NTOK * TOPK * 2;
        float4 v = *reinterpret_cast<const float4*>(&logits[rr * OSTR + cc * 4]);
        *reinterpret_cast<float4*>(&gout[(size_t)(t0 + rr) * NEXP + cc * 4]) = v;
    }
}

extern "C" void kernel_launch(void* const* d_in, const int* in_sizes, int n_in,
                              void* d_out, int out_size, void* d_ws, size_t ws_size,
                              hipStream_t stream) {
    const float* hs = (const float*)d_in[0];   // [4,4096,2048]
    const float* Wg = (const float*)d_in[1];   // [64,2048]
    const float* Wn = (const float*)d_in[2];   // [64,2048]
    const float* nz = (const float*)d_in[3];   // [4,4096,64]
    float* out = (float*)d_out;
    unsigned short* wsB = (unsigned short*)d_ws;   // 1 MB B-fragment pack (fp16 bits)

    prep_w<<<64, 512, 0, stream>>>(Wg, Wn, wsB);
    noisy_topk_router<<<NTOK / TM, 256, 0, stream>>>(hs, wsB, nz, out);
}